// Round 11
// baseline (212.343 us; speedup 1.0000x reference)
//
#include <hip/hip_runtime.h>
#include <math.h>

typedef short s16x8 __attribute__((ext_vector_type(8)));
typedef short s16x4 __attribute__((ext_vector_type(4)));
typedef float f32x4 __attribute__((ext_vector_type(4)));

__device__ __forceinline__ void bsplit(float x, short& hi, short& lo) {
    unsigned u  = __float_as_uint(x);
    unsigned uh = u & 0xFFFF0000u;
    hi = (short)(uh >> 16);
    float r = x - __uint_as_float(uh);
    lo = (short)(__float_as_uint(r) >> 16);
}

#define MFMA_B16(A, B, C) __builtin_amdgcn_mfma_f32_16x16x32_bf16((A), (B), (C), 0, 0, 0)

// Single fused kernel: 1 batch per block, 512 thr (8 waves).
// Weight-stationary; 8 el-tiles of 16; 3-chain MFMA ILP per phase; parallel tail.
__global__ __launch_bounds__(512, 4)
void ds_all(const float* __restrict__ dyn, const float* __restrict__ stat,
            const float* __restrict__ pw1, const float* __restrict__ pb1,
            const float* __restrict__ pw2, const float* __restrict__ pb2,
            const float* __restrict__ pw3, const float* __restrict__ pb3,
            const float* __restrict__ rw1, const float* __restrict__ rb1,
            const float* __restrict__ rw2, const float* __restrict__ rb2,
            const float* __restrict__ rw3, const float* __restrict__ rb3,
            const float* __restrict__ qw1, const float* __restrict__ qb1,
            const float* __restrict__ qw2, const float* __restrict__ qb2,
            const float* __restrict__ qw3, const float* __restrict__ qb3,
            float* __restrict__ out) {
    const int tid = threadIdx.x;
    const int w = tid >> 6, l = tid & 63, ln = l & 15, l4 = l >> 4;
    const int b = blockIdx.x;

    __shared__ __align__(16) float xs[384];
    __shared__ short h1H[2048], h1L[2048];   // [16 el][128 k], col ^= (el&7)<<3
    __shared__ short h2H[2048], h2L[2048];   // [16 el][128 o], col ^= (el&7)<<3
    __shared__ __align__(16) float pooledS[80];
    __shared__ __align__(16) float r1s[64], r2s[64], xcat[48], q1s[200], q2s[104];
    __shared__ float logits[3];

    // ---- stage dyn[b] ----
    if (tid < 96)
        *(f32x4*)(xs + tid * 4) = *(const f32x4*)(dyn + (size_t)b * 384 + tid * 4);

    // ---- zero h2 cols 112..127 (never written; must be finite for MFMA) ----
    if (tid < 128) {
        const int t = tid & 63, row = t >> 2, q = t & 3;
        const int col = (112 + q * 4) ^ ((row & 7) << 3);
        s16x4 z = 0;
        short* dst = (tid < 64) ? h2H : h2L;
        *(s16x4*)(dst + row * 128 + col) = z;
    }

    // ---- per-thread w1 coeffs (h1-gen role: row=tid>>5, k0=(tid&31)*4) ----
    const int grow = tid >> 5;
    const int k0   = (tid & 31) * 4;
    f32x4 c1_0, c1_1, c1_2, c1_3;
    #define LDC(J, C) do { const int k = k0 + (J);                              \
        if (k < 120) { C.x = pw1[k*3]; C.y = pw1[k*3+1]; C.z = pw1[k*3+2];      \
                       C.w = pb1[k]; }                                          \
        else C = 0.f; } while (0)
    LDC(0, c1_0); LDC(1, c1_1); LDC(2, c1_2); LDC(3, c1_3);
    #undef LDC

    // ---- stationary weight frags (A-operand): w2 for w<7, w3 for w<5 ----
    const int arow = 16 * w + ln;
    s16x8 w2h0=0,w2h1=0,w2h2=0,w2h3=0, w2l0=0,w2l1=0,w2l2=0,w2l3=0;
    s16x8 w3h0=0,w3h1=0,w3h2=0,w3h3=0, w3l0=0,w3l1=0,w3l2=0,w3l3=0;
    f32x4 bb2 = 0.f, bb3 = 0.f;
    if (w < 7) {
        #define LDW2(KS, DH, DL) do { s16x8 vh, vl;                             \
            _Pragma("unroll")                                                   \
            for (int j = 0; j < 8; ++j) {                                       \
                const int c = (KS) * 32 + l4 * 8 + j;                           \
                float v = (arow < 100 && c < 120) ? pw2[arow * 120 + c] : 0.f;  \
                short hi, lo; bsplit(v, hi, lo); vh[j] = hi; vl[j] = lo;        \
            } DH = vh; DL = vl; } while (0)
        LDW2(0, w2h0, w2l0); LDW2(1, w2h1, w2l1);
        LDW2(2, w2h2, w2l2); LDW2(3, w2h3, w2l3);
        #undef LDW2
        const int o0 = 16 * w + 4 * l4;
        #pragma unroll
        for (int r = 0; r < 4; ++r) bb2[r] = (o0 + r < 100) ? pb2[o0 + r] : 0.f;
    }
    if (w < 5) {
        #define LDW3(KS, DH, DL) do { s16x8 vh, vl;                             \
            _Pragma("unroll")                                                   \
            for (int j = 0; j < 8; ++j) {                                       \
                const int c = (KS) * 32 + l4 * 8 + j;                           \
                float v = (c < 100) ? pw3[arow * 100 + c] : 0.f;                \
                short hi, lo; bsplit(v, hi, lo); vh[j] = hi; vl[j] = lo;        \
            } DH = vh; DL = vl; } while (0)
        LDW3(0, w3h0, w3l0); LDW3(1, w3h1, w3l1);
        LDW3(2, w3h2, w3l2); LDW3(3, w3h3, w3l3);
        #undef LDW3
        bb3 = *(const f32x4*)(pb3 + 16 * w + 4 * l4);
    }
    __syncthreads();

    float pool0 = 0.f, pool1 = 0.f, pool2 = 0.f, pool3 = 0.f;
    const int swzR = (ln & 7) << 3;         // read-side swizzle (row = ln)
    const int swzG = (grow & 7) << 3;       // gen-side swizzle  (row = grow)
    #define HIDX(KS) (ln * 128 + ((((KS) * 32) + l4 * 8) ^ swzR))

    #pragma unroll 1
    for (int T = 0; T < 8; ++T) {
        // ---- gen h1 tile: thread -> 4 values of row grow, k0..k0+3 ----
        {
            const int el = 16 * T + grow;
            const float x0 = xs[el * 3], x1 = xs[el * 3 + 1], x2 = xs[el * 3 + 2];
            s16x4 vh, vl;
            #define GEN(J, C) do {                                              \
                float v = fmaf(x0, C.x, fmaf(x1, C.y, fmaf(x2, C.z, C.w)));     \
                v = fmaxf(v, 0.f);                                              \
                short hi, lo; bsplit(v, hi, lo); vh[J] = hi; vl[J] = lo;        \
            } while (0)
            GEN(0, c1_0); GEN(1, c1_1); GEN(2, c1_2); GEN(3, c1_3);
            #undef GEN
            const int idx = grow * 128 + (k0 ^ swzG);
            *(s16x4*)(h1H + idx) = vh;
            *(s16x4*)(h1L + idx) = vl;
        }
        __syncthreads();

        // ---- L2: wave w<7 computes h2 o-tile n2=w; 3 indep 4-deep chains ----
        if (w < 7) {
            f32x4 a2h = 0.f, a2x = 0.f, a2y = 0.f;
            __builtin_amdgcn_s_setprio(1);
            {   // ks 0-1 frags, 6 MFMA
                const s16x8 bh0 = *(const s16x8*)(h1H + HIDX(0));
                const s16x8 bl0 = *(const s16x8*)(h1L + HIDX(0));
                const s16x8 bh1v = *(const s16x8*)(h1H + HIDX(1));
                const s16x8 bl1v = *(const s16x8*)(h1L + HIDX(1));
                a2h = MFMA_B16(w2h0, bh0, a2h);
                a2x = MFMA_B16(w2h0, bl0, a2x);
                a2y = MFMA_B16(w2l0, bh0, a2y);
                a2h = MFMA_B16(w2h1, bh1v, a2h);
                a2x = MFMA_B16(w2h1, bl1v, a2x);
                a2y = MFMA_B16(w2l1, bh1v, a2y);
            }
            {   // ks 2-3 frags, 6 MFMA
                const s16x8 bh2 = *(const s16x8*)(h1H + HIDX(2));
                const s16x8 bl2 = *(const s16x8*)(h1L + HIDX(2));
                const s16x8 bh3 = *(const s16x8*)(h1H + HIDX(3));
                const s16x8 bl3 = *(const s16x8*)(h1L + HIDX(3));
                a2h = MFMA_B16(w2h2, bh2, a2h);
                a2x = MFMA_B16(w2h2, bl2, a2x);
                a2y = MFMA_B16(w2l2, bh2, a2y);
                a2h = MFMA_B16(w2h3, bh3, a2h);
                a2x = MFMA_B16(w2h3, bl3, a2x);
                a2y = MFMA_B16(w2l3, bh3, a2y);
            }
            __builtin_amdgcn_s_setprio(0);
            s16x4 oh, ol;
            #pragma unroll
            for (int r = 0; r < 4; ++r) {
                float v = fmaxf(a2h[r] + a2x[r] + a2y[r] + bb2[r], 0.f);
                short hi, lo; bsplit(v, hi, lo);
                oh[r] = hi; ol[r] = lo;
            }
            const int idx2 = ln * 128 + ((16 * w + 4 * l4) ^ swzR);
            *(s16x4*)(h2H + idx2) = oh;
            *(s16x4*)(h2L + idx2) = ol;
        }
        __syncthreads();

        // ---- L3 + pool: wave w<5 computes o3-tile n3=w ----
        if (w < 5) {
            f32x4 a3 = 0.f, a3x = 0.f, a3y = 0.f;
            __builtin_amdgcn_s_setprio(1);
            {
                const s16x8 bh0 = *(const s16x8*)(h2H + HIDX(0));
                const s16x8 bl0 = *(const s16x8*)(h2L + HIDX(0));
                const s16x8 bh1v = *(const s16x8*)(h2H + HIDX(1));
                const s16x8 bl1v = *(const s16x8*)(h2L + HIDX(1));
                a3  = MFMA_B16(w3h0, bh0, a3);
                a3x = MFMA_B16(w3h0, bl0, a3x);
                a3y = MFMA_B16(w3l0, bh0, a3y);
                a3  = MFMA_B16(w3h1, bh1v, a3);
                a3x = MFMA_B16(w3h1, bl1v, a3x);
                a3y = MFMA_B16(w3l1, bh1v, a3y);
            }
            {
                const s16x8 bh2 = *(const s16x8*)(h2H + HIDX(2));
                const s16x8 bl2 = *(const s16x8*)(h2L + HIDX(2));
                const s16x8 bh3 = *(const s16x8*)(h2H + HIDX(3));
                const s16x8 bl3 = *(const s16x8*)(h2L + HIDX(3));
                a3  = MFMA_B16(w3h2, bh2, a3);
                a3x = MFMA_B16(w3h2, bl2, a3x);
                a3y = MFMA_B16(w3l2, bh2, a3y);
                a3  = MFMA_B16(w3h3, bh3, a3);
                a3x = MFMA_B16(w3h3, bl3, a3x);
                a3y = MFMA_B16(w3l3, bh3, a3y);
            }
            __builtin_amdgcn_s_setprio(0);
            pool0 += fmaxf(a3[0] + a3x[0] + a3y[0] + bb3[0], 0.f);
            pool1 += fmaxf(a3[1] + a3x[1] + a3y[1] + bb3[1], 0.f);
            pool2 += fmaxf(a3[2] + a3x[2] + a3y[2] + bb3[2], 0.f);
            pool3 += fmaxf(a3[3] + a3x[3] + a3y[3] + bb3[3], 0.f);
        }
        __syncthreads();
    }
    #undef HIDX

    // ---- pool reduce over ln, write pooledS ----
    if (w < 5) {
        #pragma unroll
        for (int d = 1; d < 16; d <<= 1) {
            pool0 += __shfl_xor(pool0, d);
            pool1 += __shfl_xor(pool1, d);
            pool2 += __shfl_xor(pool2, d);
            pool3 += __shfl_xor(pool3, d);
        }
        if (ln == 0) {
            const int o0 = 16 * w + 4 * l4;
            pooledS[o0 + 0] = pool0;
            pooledS[o0 + 1] = pool1;
            pooledS[o0 + 2] = pool2;
            pooledS[o0 + 3] = pool3;
        }
    }
    __syncthreads();

    // ---- fused tail, parallelized: 4 (or 2) threads per output + shfl reduce ----
    if (tid < 240) {                       // rho1: 60 outs x 20 f32x4 chunks
        const int o = tid >> 2, p = tid & 3;
        float a = 0.f;
        for (int c = p; c < 20; c += 4) {
            f32x4 pv = *(const f32x4*)(pooledS + c * 4);
            f32x4 wv = *(const f32x4*)(rw1 + o * 80 + c * 4);
            a += pv.x * wv.x + pv.y * wv.y + pv.z * wv.z + pv.w * wv.w;
        }
        a += __shfl_xor(a, 1);
        a += __shfl_xor(a, 2);
        if (p == 0) r1s[o] = fmaxf(a + rb1[o], 0.f);
    }
    __syncthreads();
    if (tid < 240) {                       // rho2: 60 outs x 15 chunks
        const int o = tid >> 2, p = tid & 3;
        float a = 0.f;
        for (int c = p; c < 15; c += 4) {
            f32x4 pv = *(const f32x4*)(r1s + c * 4);
            f32x4 wv = *(const f32x4*)(rw2 + o * 60 + c * 4);
            a += pv.x * wv.x + pv.y * wv.y + pv.z * wv.z + pv.w * wv.w;
        }
        a += __shfl_xor(a, 1);
        a += __shfl_xor(a, 2);
        if (p == 0) r2s[o] = fmaxf(a + rb2[o], 0.f);
    }
    __syncthreads();
    if (tid < 160) {                       // rho3: 40 outs x 15 chunks (no relu)
        const int o = tid >> 2, p = tid & 3;
        float a = 0.f;
        for (int c = p; c < 15; c += 4) {
            f32x4 pv = *(const f32x4*)(r2s + c * 4);
            f32x4 wv = *(const f32x4*)(rw3 + o * 60 + c * 4);
            a += pv.x * wv.x + pv.y * wv.y + pv.z * wv.z + pv.w * wv.w;
        }
        a += __shfl_xor(a, 1);
        a += __shfl_xor(a, 2);
        if (p == 0) xcat[o] = a + rb3[o];
    }
    if (tid >= 160 && tid < 163) xcat[40 + tid - 160] = stat[(size_t)b * 3 + (tid - 160)];
    __syncthreads();
    if (tid < 400) {                       // q1: 200 outs x 43 scalar, 2/out
        const int o = tid >> 1, p = tid & 1;
        float a = 0.f;
        const float* wv = qw1 + o * 43;
        for (int k = p; k < 43; k += 2) a += xcat[k] * wv[k];
        a += __shfl_xor(a, 1);
        if (p == 0) q1s[o] = fmaxf(a + qb1[o], 0.f);
    }
    __syncthreads();
    if (tid < 400) {                       // q2: 100 outs x 50 chunks, 4/out
        const int o = tid >> 2, p = tid & 3;
        float a = 0.f;
        for (int c = p; c < 50; c += 4) {
            f32x4 pv = *(const f32x4*)(q1s + c * 4);
            f32x4 wv = *(const f32x4*)(qw2 + o * 200 + c * 4);
            a += pv.x * wv.x + pv.y * wv.y + pv.z * wv.z + pv.w * wv.w;
        }
        a += __shfl_xor(a, 1);
        a += __shfl_xor(a, 2);
        if (p == 0) q2s[o] = fmaxf(a + qb2[o], 0.f);
    }
    __syncthreads();
    if (tid < 96) {                        // q3: 3 outs x 100, 32/out
        int o = tid >> 5, l2 = tid & 31;
        float a = 0.0f;
        for (int k = l2; k < 100; k += 32) a += q2s[k] * qw3[o * 100 + k];
        #pragma unroll
        for (int d = 16; d > 0; d >>= 1) a += __shfl_down(a, d, 32);
        if (l2 == 0) logits[o] = a + qb3[o];
    }
    __syncthreads();
    if (tid < 3) {
        float l0 = logits[0], l1 = logits[1], l2v = logits[2];
        float m  = fmaxf(l0, fmaxf(l1, l2v));
        float e0 = __expf(l0 - m), e1 = __expf(l1 - m), e2 = __expf(l2v - m);
        float inv = 1.0f / (e0 + e1 + e2);
        float mine = (tid == 0) ? e0 : ((tid == 1) ? e1 : e2);
        out[(size_t)b * 3 + tid] = mine * inv;
    }
}

extern "C" void kernel_launch(void* const* d_in, const int* in_sizes, int n_in,
                              void* d_out, int out_size, void* d_ws, size_t ws_size,
                              hipStream_t stream) {
    const float* dyn  = (const float*)d_in[0];
    const float* stat = (const float*)d_in[1];
    const float* pw1  = (const float*)d_in[2];
    const float* pb1  = (const float*)d_in[3];
    const float* pw2  = (const float*)d_in[4];
    const float* pb2  = (const float*)d_in[5];
    const float* pw3  = (const float*)d_in[6];
    const float* pb3  = (const float*)d_in[7];
    const float* rw1  = (const float*)d_in[8];
    const float* rb1  = (const float*)d_in[9];
    const float* rw2  = (const float*)d_in[10];
    const float* rb2  = (const float*)d_in[11];
    const float* rw3  = (const float*)d_in[12];
    const float* rb3  = (const float*)d_in[13];
    const float* qw1  = (const float*)d_in[14];
    const float* qb1  = (const float*)d_in[15];
    const float* qw2  = (const float*)d_in[16];
    const float* qb2  = (const float*)d_in[17];
    const float* qw3  = (const float*)d_in[18];
    const float* qb3  = (const float*)d_in[19];
    float* out = (float*)d_out;

    const int B = in_sizes[0] / 384;   // 2048
    ds_all<<<dim3(B), dim3(512), 0, stream>>>(dyn, stat,
        pw1, pb1, pw2, pb2, pw3, pb3,
        rw1, rb1, rw2, rb2, rw3, rb3,
        qw1, qb1, qw2, qb2, qw3, qb3, out);
}